// Round 7
// baseline (153.756 us; speedup 1.0000x reference)
//
#include <hip/hip_runtime.h>
#include <hip/hip_bf16.h>
#include <cstdint>
#include <cstddef>

#define I_F   1024
#define O_F   1024
#define BATCH 4096
#define KDIM  9216   // 9 * 1024 : j-major (j=0 base/swish, j=1..8 spline bases)
#define EPSC  1e-7f

typedef __bf16 bf16;
typedef __bf16 bf16x4 __attribute__((ext_vector_type(4)));
typedef __bf16 bf16x8 __attribute__((ext_vector_type(8)));
typedef float  f32x4  __attribute__((ext_vector_type(4)));
typedef float  f32x16 __attribute__((ext_vector_type(16)));

// ---------------------------------------------------------------------------
// Kernel 1: activations A[b][j*1024+i] = {swish(x), bases[0..7]}  (bf16)
// ---------------------------------------------------------------------------
__global__ __launch_bounds__(256) void act_kernel(const float* __restrict__ x,
                                                  const float* __restrict__ grid,
                                                  bf16* __restrict__ A) {
    int t  = blockIdx.x * 256 + threadIdx.x;     // 1,048,576 threads
    int b  = t >> 8;
    int i0 = (t & 255) << 2;
    f32x4 xv4 = *(const f32x4*)(x + (size_t)b * I_F + i0);

    float g[12];
#pragma unroll
    for (int j = 0; j < 12; ++j) g[j] = grid[j];
    float r1[11], r2[10], r3[9];
#pragma unroll
    for (int j = 0; j < 11; ++j) r1[j] = __builtin_amdgcn_rcpf(g[j + 1] - g[j] + EPSC);
#pragma unroll
    for (int j = 0; j < 10; ++j) r2[j] = __builtin_amdgcn_rcpf(g[j + 2] - g[j] + EPSC);
#pragma unroll
    for (int j = 0; j < 9;  ++j) r3[j] = __builtin_amdgcn_rcpf(g[j + 3] - g[j] + EPSC);

    float sw[4];
    float bs8[4][8];
#pragma unroll
    for (int e = 0; e < 4; ++e) {
        float xv = xv4[e];
        float bas[11];
#pragma unroll
        for (int j = 0; j < 11; ++j)
            bas[j] = (xv >= g[j] && xv < g[j + 1]) ? 1.0f : 0.0f;
#pragma unroll
        for (int j = 0; j < 10; ++j)
            bas[j] = (xv - g[j]) * r1[j] * bas[j] + (g[j + 2] - xv) * r1[j + 1] * bas[j + 1];
#pragma unroll
        for (int j = 0; j < 9; ++j)
            bas[j] = (xv - g[j]) * r2[j] * bas[j] + (g[j + 3] - xv) * r2[j + 1] * bas[j + 1];
#pragma unroll
        for (int j = 0; j < 8; ++j)
            bas[j] = (xv - g[j]) * r3[j] * bas[j] + (g[j + 4] - xv) * r3[j + 1] * bas[j + 1];
#pragma unroll
        for (int k = 0; k < 8; ++k) bs8[e][k] = bas[k];
        float sig = 1.0f / (1.0f + __expf(-xv));
        sw[e] = xv * sig;
    }

    bf16* outp = A + (size_t)b * KDIM + i0;
    *(bf16x4*)(outp) = (bf16x4){(bf16)sw[0], (bf16)sw[1], (bf16)sw[2], (bf16)sw[3]};
#pragma unroll
    for (int k = 0; k < 8; ++k)
        *(bf16x4*)(outp + (size_t)(k + 1) * 1024) =
            (bf16x4){(bf16)bs8[0][k], (bf16)bs8[1][k], (bf16)bs8[2][k], (bf16)bs8[3][k]};
}

// ---------------------------------------------------------------------------
// Kernel 2: Wt[o][j*1024+i] = { base_scaler[i,o], spline_weight[i,o,k]*spline_scaler[i,o] }
// ---------------------------------------------------------------------------
__global__ __launch_bounds__(256) void wprep_kernel(const float* __restrict__ w,
                                                    const float* __restrict__ ss,
                                                    const float* __restrict__ bs,
                                                    bf16* __restrict__ Wt) {
    int g = blockIdx.x * 256 + threadIdx.x;      // 1024 i * 128 o-groups = 131072
    int i  = g & 1023;
    int o0 = (g >> 10) << 3;                     // 8 o per thread
#pragma unroll
    for (int oo = 0; oo < 8; ++oo) {
        int o = o0 + oo;
        size_t io = (size_t)i * 1024 + o;
        float scale = ss[io];
        float base  = bs[io];
        const float* wp = w + io * 8;
        f32x4 w0 = *(const f32x4*)(wp);
        f32x4 w1 = *(const f32x4*)(wp + 4);

        bf16* outp = Wt + (size_t)o * KDIM + i;
        outp[0] = (bf16)base;
#pragma unroll
        for (int k = 0; k < 4; ++k) outp[(size_t)(k + 1) * 1024] = (bf16)(w0[k] * scale);
#pragma unroll
        for (int k = 0; k < 4; ++k) outp[(size_t)(k + 5) * 1024] = (bf16)(w1[k] * scale);
    }
}

// ---------------------------------------------------------------------------
// Kernel 3: GEMM  out = A(4096x9216) * Wt^T(1024x9216), bf16 MFMA 32x32x16.
// 256x256 tile, 8 waves (2Mx4N), BK=64 (128-B rows), double-buffered 128KB LDS.
// 4 phases per K-tile (one per k16-slice): {6 ds_read; barrier; lgkmcnt(0);
// setprio; 8 MFMA; setprio; barrier} -- m201 phase template.
// Bank pattern: unit = (2ks+hi)^(row&7), 128-B rows => row-independent bank
// base + 3-bit XOR spread = R2-proven conflict-free class. Pre-swizzled DMA
// source, linear LDS dest (rule 21). vmcnt(0) at tile top waits on loads
// issued ~4 phases earlier (free).
// ---------------------------------------------------------------------------
__device__ __forceinline__ void load_lds16(const bf16* g, bf16* l) {
    __builtin_amdgcn_global_load_lds(
        (__attribute__((address_space(1))) void*)g,
        (__attribute__((address_space(3))) void*)l, 16, 0, 0);
}

__global__ __launch_bounds__(512, 1) void gemm_kernel(const bf16* __restrict__ A,
                                                      const bf16* __restrict__ Wt,
                                                      float* __restrict__ out,
                                                      float* __restrict__ parts,
                                                      int split, int ktiles) {  // BK=64 units
    __shared__ __align__(16) bf16 SA[2][16384];   // 2 x 32 KB : 256 rows x 64 bf16
    __shared__ __align__(16) bf16 SB[2][16384];

    const int t    = threadIdx.x;
    const int lane = t & 63;
    const int w    = t >> 6;           // 0..7

    // XCD-chunked decode over the 64 output tiles x split
    const int nwg8 = gridDim.x >> 3;
    const int L    = (blockIdx.x & 7) * nwg8 + (blockIdx.x >> 3);
    const int nper = split << 4;       // blocks per tn-column group
    const int tn   = L / nper;
    const int rem  = L - tn * nper;
    const int s    = rem >> 4;         // split index
    const int tm   = rem & 15;

    const int row0 = tm << 8;
    const int col0 = tn << 8;
    const size_t k0 = (size_t)s * ktiles * 64;
    float* dst = (s == 0) ? out : parts + (size_t)(s - 1) * BATCH * O_F;

    // ---- staging (linear LDS dest; pre-swizzled global source) ----
    // DMA instr covers 8 rows x 8 16B-units; lane l -> row +(l>>3), phys unit l&7.
    // content(phys p, row r) = logical unit p ^ (r&7).
    const int l3 = lane >> 3;                        // 0..7 row-in-group
    const int lc = (lane & 7) ^ l3;                  // pre-swizzled 16B-unit
    const bf16* gA0 = A  + (size_t)(row0 + w * 32 + l3) * KDIM + k0 + lc * 8;
    const bf16* gB0 = Wt + (size_t)(col0 + w * 32 + l3) * KDIM + k0 + lc * 8;

    // ---- fragment read coords ----
    const int wm  = w >> 2;            // 0..1  (M half: 128 rows)
    const int wn  = w & 3;             // 0..3  (N quarter: 64 cols)
    const int r31 = lane & 31;
    const int hi  = lane >> 5;
    const int rx  = r31 & 7;           // row&7 for read-side swizzle

    f32x16 acc[4][2];
#pragma unroll
    for (int mt = 0; mt < 4; ++mt)
#pragma unroll
        for (int nt = 0; nt < 2; ++nt)
#pragma unroll
            for (int r = 0; r < 16; ++r) acc[mt][nt][r] = 0.f;

    auto stage = [&](int j) {
        const int buf = j & 1;
        const bf16* pa = gA0 + (size_t)j * 64;
        const bf16* pb = gB0 + (size_t)j * 64;
#pragma unroll
        for (int q = 0; q < 4; ++q) {
            load_lds16(pa + (size_t)q * 8 * KDIM, &SA[buf][(w * 32 + q * 8) * 64]);
            load_lds16(pb + (size_t)q * 8 * KDIM, &SB[buf][(w * 32 + q * 8) * 64]);
        }
    };

    stage(0);

    for (int j = 0; j < ktiles; ++j) {
        asm volatile("s_waitcnt vmcnt(0)" ::: "memory");  // tile j landed (issued ~1 tile ago)
        __builtin_amdgcn_s_barrier();                     // all waves see tile j
        asm volatile("" ::: "memory");
        if (j + 1 < ktiles) stage(j + 1);                 // into buf read 2 tiles ago (safe)
        const int buf = j & 1;
#pragma unroll
        for (int p = 0; p < 4; ++p) {                     // 4 phases: k16-slice each
            bf16x8 af[4], bv[2];
#pragma unroll
            for (int mt = 0; mt < 4; ++mt)
                af[mt] = *(const bf16x8*)&SA[buf][(wm * 128 + mt * 32 + r31) * 64
                                                 + (((p * 2 + hi) ^ rx) << 3)];
#pragma unroll
            for (int nt = 0; nt < 2; ++nt)
                bv[nt] = *(const bf16x8*)&SB[buf][(wn * 64 + nt * 32 + r31) * 64
                                                 + (((p * 2 + hi) ^ rx) << 3)];
            __builtin_amdgcn_s_barrier();                 // pre-MFMA align (m201)
            asm volatile("s_waitcnt lgkmcnt(0)" ::: "memory");
            __builtin_amdgcn_s_setprio(1);
#pragma unroll
            for (int mt = 0; mt < 4; ++mt)
#pragma unroll
                for (int nt = 0; nt < 2; ++nt)
                    acc[mt][nt] = __builtin_amdgcn_mfma_f32_32x32x16_bf16(
                        af[mt], bv[nt], acc[mt][nt], 0, 0, 0);
            __builtin_amdgcn_s_setprio(0);
            __builtin_amdgcn_s_barrier();                 // post-MFMA align
        }
    }

    // Epilogue: 32x32 C/D layout: col=lane&31, row=(reg&3)+8*(reg>>2)+4*(lane>>5) [m74/m101]
    float* cp = dst + (size_t)(row0 + wm * 128) * O_F + col0 + wn * 64 + r31;
#pragma unroll
    for (int mt = 0; mt < 4; ++mt)
#pragma unroll
        for (int nt = 0; nt < 2; ++nt)
#pragma unroll
            for (int r = 0; r < 16; ++r) {
                int rl = (r & 3) + 8 * (r >> 2) + 4 * hi;
                cp[(size_t)(mt * 32 + rl) * O_F + nt * 32] = acc[mt][nt][r];
            }
}

// ---------------------------------------------------------------------------
// Kernel 4: out += sum(parts[0..np))   (split-K reduce), f32x4
// ---------------------------------------------------------------------------
__global__ __launch_bounds__(256) void add_kernel(float* __restrict__ out,
                                                  const float* __restrict__ parts,
                                                  int np) {
    int t = blockIdx.x * 256 + threadIdx.x;
    f32x4 a = *((const f32x4*)out + t);
    for (int p = 0; p < np; ++p)
        a += *((const f32x4*)(parts + (size_t)p * BATCH * O_F) + t);
    *((f32x4*)out + t) = a;
}

// ---------------------------------------------------------------------------
extern "C" void kernel_launch(void* const* d_in, const int* in_sizes, int n_in,
                              void* d_out, int out_size, void* d_ws, size_t ws_size,
                              hipStream_t stream) {
    const float* x    = (const float*)d_in[0];
    const float* grid = (const float*)d_in[1];
    const float* w    = (const float*)d_in[2];
    const float* ss   = (const float*)d_in[3];
    const float* bs   = (const float*)d_in[4];
    float* out = (float*)d_out;

    const size_t nA = (size_t)BATCH * KDIM * 2;   // 75.5 MB
    const size_t nW = (size_t)O_F   * KDIM * 2;   // 18.9 MB
    const size_t nP = (size_t)BATCH * O_F  * 4;   // 16.8 MB per partial

    bf16* A  = (bf16*)d_ws;
    bf16* Wt = (bf16*)((char*)d_ws + nA);
    float* parts = (float*)((char*)d_ws + nA + nW);

    act_kernel<<<(BATCH * I_F / 4) / 256, 256, 0, stream>>>(x, grid, A);
    wprep_kernel<<<(I_F * O_F / 8) / 256, 256, 0, stream>>>(w, ss, bs, Wt);

    int split = (ws_size >= nA + nW + 3 * nP) ? 4
              : (ws_size >= nA + nW + nP)     ? 2 : 1;
    // ktiles in BK=64 units: 9216/64 = 144 total
    gemm_kernel<<<64 * split, 512, 0, stream>>>(A, Wt, out, parts, split, 144 / split);
    if (split > 1)
        add_kernel<<<(BATCH * O_F / 4) / 256, 256, 0, stream>>>(out, parts, split - 1);
}

// Round 8
// 143.839 us; speedup vs baseline: 1.0689x; 1.0689x over previous
//
#include <hip/hip_runtime.h>
#include <hip/hip_bf16.h>
#include <cstdint>
#include <cstddef>

#define I_F   1024
#define O_F   1024
#define BATCH 4096
#define KDIM  9216   // 9 * 1024 : j-major (j=0 base/swish, j=1..8 spline bases)
#define EPSC  1e-7f

typedef __bf16 bf16;
typedef __bf16 bf16x4 __attribute__((ext_vector_type(4)));
typedef __bf16 bf16x8 __attribute__((ext_vector_type(8)));
typedef float  f32x4  __attribute__((ext_vector_type(4)));
typedef float  f32x16 __attribute__((ext_vector_type(16)));

// ---------------------------------------------------------------------------
// Kernel 1: activations A[b][j*1024+i] = {swish(x), bases[0..7]}  (bf16)
// ---------------------------------------------------------------------------
__global__ __launch_bounds__(256) void act_kernel(const float* __restrict__ x,
                                                  const float* __restrict__ grid,
                                                  bf16* __restrict__ A) {
    int t  = blockIdx.x * 256 + threadIdx.x;     // 1,048,576 threads
    int b  = t >> 8;
    int i0 = (t & 255) << 2;
    f32x4 xv4 = *(const f32x4*)(x + (size_t)b * I_F + i0);

    float g[12];
#pragma unroll
    for (int j = 0; j < 12; ++j) g[j] = grid[j];
    float r1[11], r2[10], r3[9];
#pragma unroll
    for (int j = 0; j < 11; ++j) r1[j] = __builtin_amdgcn_rcpf(g[j + 1] - g[j] + EPSC);
#pragma unroll
    for (int j = 0; j < 10; ++j) r2[j] = __builtin_amdgcn_rcpf(g[j + 2] - g[j] + EPSC);
#pragma unroll
    for (int j = 0; j < 9;  ++j) r3[j] = __builtin_amdgcn_rcpf(g[j + 3] - g[j] + EPSC);

    float sw[4];
    float bs8[4][8];
#pragma unroll
    for (int e = 0; e < 4; ++e) {
        float xv = xv4[e];
        float bas[11];
#pragma unroll
        for (int j = 0; j < 11; ++j)
            bas[j] = (xv >= g[j] && xv < g[j + 1]) ? 1.0f : 0.0f;
#pragma unroll
        for (int j = 0; j < 10; ++j)
            bas[j] = (xv - g[j]) * r1[j] * bas[j] + (g[j + 2] - xv) * r1[j + 1] * bas[j + 1];
#pragma unroll
        for (int j = 0; j < 9; ++j)
            bas[j] = (xv - g[j]) * r2[j] * bas[j] + (g[j + 3] - xv) * r2[j + 1] * bas[j + 1];
#pragma unroll
        for (int j = 0; j < 8; ++j)
            bas[j] = (xv - g[j]) * r3[j] * bas[j] + (g[j + 4] - xv) * r3[j + 1] * bas[j + 1];
#pragma unroll
        for (int k = 0; k < 8; ++k) bs8[e][k] = bas[k];
        float sig = 1.0f / (1.0f + __expf(-xv));
        sw[e] = xv * sig;
    }

    bf16* outp = A + (size_t)b * KDIM + i0;
    *(bf16x4*)(outp) = (bf16x4){(bf16)sw[0], (bf16)sw[1], (bf16)sw[2], (bf16)sw[3]};
#pragma unroll
    for (int k = 0; k < 8; ++k)
        *(bf16x4*)(outp + (size_t)(k + 1) * 1024) =
            (bf16x4){(bf16)bs8[0][k], (bf16)bs8[1][k], (bf16)bs8[2][k], (bf16)bs8[3][k]};
}

// ---------------------------------------------------------------------------
// Kernel 2: Wt[o][j*1024+i] = { base_scaler[i,o], spline_weight[i,o,k]*spline_scaler[i,o] }
// ---------------------------------------------------------------------------
__global__ __launch_bounds__(256) void wprep_kernel(const float* __restrict__ w,
                                                    const float* __restrict__ ss,
                                                    const float* __restrict__ bs,
                                                    bf16* __restrict__ Wt) {
    int g = blockIdx.x * 256 + threadIdx.x;      // 1024 i * 128 o-groups = 131072
    int i  = g & 1023;
    int o0 = (g >> 10) << 3;                     // 8 o per thread
#pragma unroll
    for (int oo = 0; oo < 8; ++oo) {
        int o = o0 + oo;
        size_t io = (size_t)i * 1024 + o;
        float scale = ss[io];
        float base  = bs[io];
        const float* wp = w + io * 8;
        f32x4 w0 = *(const f32x4*)(wp);
        f32x4 w1 = *(const f32x4*)(wp + 4);

        bf16* outp = Wt + (size_t)o * KDIM + i;
        outp[0] = (bf16)base;
#pragma unroll
        for (int k = 0; k < 4; ++k) outp[(size_t)(k + 1) * 1024] = (bf16)(w0[k] * scale);
#pragma unroll
        for (int k = 0; k < 4; ++k) outp[(size_t)(k + 5) * 1024] = (bf16)(w1[k] * scale);
    }
}

// ---------------------------------------------------------------------------
// Kernel 3: GEMM  out = A(4096x9216) * Wt^T(1024x9216), bf16 MFMA 32x32x16.
// R8 = R6's proven 86us kernel (256x256 tile, 8 waves 2Mx4N, BK=32, quad-buffer
// LDS, counted vmcnt(8), 1 barrier/K-tile, loose compiler schedule) +
//  (a) wave-parity k16-slice stagger: even waves order (0,1), odd (1,0) so
//      co-SIMD waves anti-phase their read-burst vs MFMA-burst;
//  (b) stage issued before frag reads (HBM starts earlier);
//  (c) split-K partials stored as bf16 (halves partial traffic).
// ---------------------------------------------------------------------------
__device__ __forceinline__ void load_lds16(const bf16* g, bf16* l) {
    __builtin_amdgcn_global_load_lds(
        (__attribute__((address_space(1))) void*)g,
        (__attribute__((address_space(3))) void*)l, 16, 0, 0);
}

__global__ __launch_bounds__(512, 2) void gemm_kernel(const bf16* __restrict__ A,
                                                      const bf16* __restrict__ Wt,
                                                      float* __restrict__ out,
                                                      bf16* __restrict__ parts,
                                                      int split, int ktiles) {  // BK=32 units
    __shared__ __align__(16) bf16 SA[4][8192];   // 4 slots x 16KB (256 rows x 32 k)
    __shared__ __align__(16) bf16 SB[4][8192];

    const int t    = threadIdx.x;
    const int lane = t & 63;
    const int w    = t >> 6;           // 0..7

    // XCD-chunked decode: each XCD owns a contiguous L-range sharing one tn panel.
    const int nwg8 = gridDim.x >> 3;
    const int L    = (blockIdx.x & 7) * nwg8 + (blockIdx.x >> 3);
    const int nper = split << 4;
    const int tn   = L / nper;
    const int rem  = L - tn * nper;
    const int s    = rem >> 4;
    const int tm   = rem & 15;

    const int row0 = tm << 8;
    const int col0 = tn << 8;
    const size_t k0 = (size_t)s * ktiles * 32;

    // ---- staging (linear LDS dest; pre-swizzled global source) ----
    // content(phys unit p, row r) = logical unit p ^ ((r>>1)&3)
    const int sr = lane >> 2;                         // 0..15
    const int lc = (lane & 3) ^ ((lane >> 3) & 3);    // pre-swizzled 16B-unit
    const bf16* gA0 = A  + (size_t)(row0 + w * 16 + sr) * KDIM + k0 + lc * 8;
    const bf16* gB0 = Wt + (size_t)(col0 + w * 16 + sr) * KDIM + k0 + lc * 8;

    // ---- fragment read coords ----
    const int wm  = w >> 2;            // 0..1  (M half: 128 rows)
    const int wn  = w & 3;             // 0..3  (N quarter: 64 cols)
    const int r31 = lane & 31;
    const int hi  = lane >> 5;
    const int swb = (r31 >> 1) & 3;    // read-side swizzle (row bits 1-2)
    const int ks0 = w & 1;             // wave-parity stagger

    f32x16 acc[4][2];
#pragma unroll
    for (int mt = 0; mt < 4; ++mt)
#pragma unroll
        for (int nt = 0; nt < 2; ++nt)
#pragma unroll
            for (int r = 0; r < 16; ++r) acc[mt][nt][r] = 0.f;

    auto stage = [&](int j) {
        const int sl = j & 3;
        const bf16* pa = gA0 + (size_t)j * 32;
        const bf16* pb = gB0 + (size_t)j * 32;
        load_lds16(pa,                      &SA[sl][w * 512]);
        load_lds16(pa + (size_t)128 * KDIM, &SA[sl][4096 + w * 512]);
        load_lds16(pb,                      &SB[sl][w * 512]);
        load_lds16(pb + (size_t)128 * KDIM, &SB[sl][4096 + w * 512]);
    };

    auto compute = [&](int sl) {
#pragma unroll
        for (int e = 0; e < 2; ++e) {
            const int ks = ks0 ^ e;                  // staggered slice order
            bf16x8 af[4], bv[2];
#pragma unroll
            for (int mt = 0; mt < 4; ++mt)
                af[mt] = *(const bf16x8*)&SA[sl][(wm * 128 + mt * 32 + r31) * 32
                                                 + (((ks * 2 + hi) ^ swb) << 3)];
#pragma unroll
            for (int nt = 0; nt < 2; ++nt)
                bv[nt] = *(const bf16x8*)&SB[sl][(wn * 64 + nt * 32 + r31) * 32
                                                 + (((ks * 2 + hi) ^ swb) << 3)];
            __builtin_amdgcn_s_setprio(1);
#pragma unroll
            for (int mt = 0; mt < 4; ++mt)
#pragma unroll
                for (int nt = 0; nt < 2; ++nt)
                    acc[mt][nt] = __builtin_amdgcn_mfma_f32_32x32x16_bf16(
                        af[mt], bv[nt], acc[mt][nt], 0, 0, 0);
            __builtin_amdgcn_s_setprio(0);
        }
    };

    // Prologue: 3 K-tiles in flight.
    stage(0); stage(1); stage(2);

    int j = 0;
    for (; j < ktiles - 3; ++j) {
        asm volatile("s_waitcnt vmcnt(8)" ::: "memory");   // tile j landed
        __builtin_amdgcn_s_barrier();                      // all waves see tile j
        asm volatile("" ::: "memory");
        stage(j + 3);                                      // slot freed at phase j-1
        compute(j & 3);
    }
    asm volatile("s_waitcnt vmcnt(8)" ::: "memory");
    __builtin_amdgcn_s_barrier();
    asm volatile("" ::: "memory");
    compute(j & 3); ++j;
    asm volatile("s_waitcnt vmcnt(4)" ::: "memory");
    __builtin_amdgcn_s_barrier();
    asm volatile("" ::: "memory");
    compute(j & 3); ++j;
    asm volatile("s_waitcnt vmcnt(0)" ::: "memory");
    __builtin_amdgcn_s_barrier();
    asm volatile("" ::: "memory");
    compute(j & 3);

    // Epilogue: 32x32 C/D layout: col=lane&31, row=(reg&3)+8*(reg>>2)+4*(lane>>5) [m74/m101]
    if (s == 0) {
        float* cp = out + (size_t)(row0 + wm * 128) * O_F + col0 + wn * 64 + r31;
#pragma unroll
        for (int mt = 0; mt < 4; ++mt)
#pragma unroll
            for (int nt = 0; nt < 2; ++nt)
#pragma unroll
                for (int r = 0; r < 16; ++r) {
                    int rl = (r & 3) + 8 * (r >> 2) + 4 * hi;
                    cp[(size_t)(mt * 32 + rl) * O_F + nt * 32] = acc[mt][nt][r];
                }
    } else {
        bf16* cp = parts + (size_t)(s - 1) * BATCH * O_F
                 + (size_t)(row0 + wm * 128) * O_F + col0 + wn * 64 + r31;
#pragma unroll
        for (int mt = 0; mt < 4; ++mt)
#pragma unroll
            for (int nt = 0; nt < 2; ++nt)
#pragma unroll
                for (int r = 0; r < 16; ++r) {
                    int rl = (r & 3) + 8 * (r >> 2) + 4 * hi;
                    cp[(size_t)(mt * 32 + rl) * O_F + nt * 32] = (bf16)acc[mt][nt][r];
                }
    }
}

// ---------------------------------------------------------------------------
// Kernel 4: out += sum(parts[0..np))   (split-K reduce), bf16 partials
// ---------------------------------------------------------------------------
__global__ __launch_bounds__(256) void add_kernel(float* __restrict__ out,
                                                  const bf16* __restrict__ parts,
                                                  int np) {
    int t = blockIdx.x * 256 + threadIdx.x;      // 1,048,576 threads, 4 f32 each
    f32x4 a = *((const f32x4*)out + t);
    for (int p = 0; p < np; ++p) {
        bf16x4 b = *((const bf16x4*)(parts + (size_t)p * BATCH * O_F) + t);
#pragma unroll
        for (int e = 0; e < 4; ++e) a[e] += (float)b[e];
    }
    *((f32x4*)out + t) = a;
}

// ---------------------------------------------------------------------------
extern "C" void kernel_launch(void* const* d_in, const int* in_sizes, int n_in,
                              void* d_out, int out_size, void* d_ws, size_t ws_size,
                              hipStream_t stream) {
    const float* x    = (const float*)d_in[0];
    const float* grid = (const float*)d_in[1];
    const float* w    = (const float*)d_in[2];
    const float* ss   = (const float*)d_in[3];
    const float* bs   = (const float*)d_in[4];
    float* out = (float*)d_out;

    const size_t nA = (size_t)BATCH * KDIM * 2;   // 75.5 MB
    const size_t nW = (size_t)O_F   * KDIM * 2;   // 18.9 MB
    const size_t nP = (size_t)BATCH * O_F  * 2;   // 8.39 MB per bf16 partial

    bf16* A  = (bf16*)d_ws;
    bf16* Wt = (bf16*)((char*)d_ws + nA);
    bf16* parts = (bf16*)((char*)d_ws + nA + nW);

    act_kernel<<<(BATCH * I_F / 4) / 256, 256, 0, stream>>>(x, grid, A);
    wprep_kernel<<<(I_F * O_F / 8) / 256, 256, 0, stream>>>(w, ss, bs, Wt);

    int split = (ws_size >= nA + nW + 3 * nP) ? 4
              : (ws_size >= nA + nW + nP)     ? 2 : 1;
    gemm_kernel<<<64 * split, 512, 0, stream>>>(A, Wt, out, parts, split, 288 / split);
    if (split > 1)
        add_kernel<<<(BATCH * O_F / 4) / 256, 256, 0, stream>>>(out, parts, split - 1);
}